// Round 6
// baseline (102.309 us; speedup 1.0000x reference)
//
#include <hip/hip_runtime.h>

#define NA 64
#define MOVE 4
#define OBS 5124
#define ROWS 80        // dyn inner row stride (elements)
#define NB 256
#define NTASK (NB * NA)   // 16384 (b,i) tasks
#define OUTC 20
#define WPB 4             // waves per block
#define TPW 4             // tasks (i's) per wave, sequential w/ prefetch

// ws layout (bf16x8 units for frags): [0..63] wq, [64..127] wk(scaled), [128..191] wvo
// floats: [768..783] bk_scaled, [784..799] bvo
#define WS_WQ 0
#define WS_WK 64
#define WS_WV 128
#define WS_BK 768
#define WS_BVO 784

typedef __attribute__((ext_vector_type(8))) short bf16x8;
typedef __attribute__((ext_vector_type(4))) float f32x4;

__device__ __forceinline__ short f2bf(float f) {
    __bf16 h = (__bf16)f;
    return __builtin_bit_cast(short, h);
}
__device__ __forceinline__ bf16x8 mkfrag4(float a, float b, float c, float d) {
    bf16x8 t;
    t[0] = f2bf(a); t[1] = f2bf(b); t[2] = f2bf(c); t[3] = f2bf(d);
    t[4] = 0; t[5] = 0; t[6] = 0; t[7] = 0;
    return t;
}
__device__ __forceinline__ bf16x8 mkfrag8(f32x4 lo, f32x4 hi) {
    bf16x8 t;
    t[0] = f2bf(lo[0]); t[1] = f2bf(lo[1]); t[2] = f2bf(lo[2]); t[3] = f2bf(lo[3]);
    t[4] = f2bf(hi[0]); t[5] = f2bf(hi[1]); t[6] = f2bf(hi[2]); t[7] = f2bf(hi[3]);
    return t;
}

__global__ __launch_bounds__(256) void init_out_kernel(
    const float* __restrict__ inp, float* __restrict__ out)
{
    int row = blockIdx.x * 256 + threadIdx.x;   // b*NA + t
    if (row >= NTASK) return;
    const float4 mv = *(const float4*)(inp + (size_t)row * OBS);
    float4* o4 = (float4*)(out + (size_t)row * OUTC);
    float4 z = make_float4(0.f, 0.f, 0.f, 0.f);
    o4[0] = mv;
    o4[1] = z; o4[2] = z; o4[3] = z; o4[4] = z;
}

__global__ __launch_bounds__(256) void prep_kernel(
    const float* __restrict__ Wq,
    const float* __restrict__ Wk, const float* __restrict__ bk,
    const float* __restrict__ Wv, const float* __restrict__ bv,
    const float* __restrict__ Wo, const float* __restrict__ bo,
    float* __restrict__ ws)
{
    __shared__ float sWvo[256];
    const float SC = 0.36067376022224085f;   // 0.25 * log2(e)
    int tid = threadIdx.x;
    {
        int e = tid >> 4, d = tid & 15;
        float acc = 0.f;
        #pragma unroll
        for (int c = 0; c < 16; ++c) acc += Wv[e * 16 + c] * Wo[c * 16 + d];
        sWvo[e * 16 + d] = acc;
    }
    __syncthreads();
    if (tid < 64) {
        int g = tid >> 4, c = tid & 15;
        bf16x8 q, k, v;
        #pragma unroll
        for (int r = 0; r < 4; ++r) {
            q[r] = f2bf(Wq[(4 * g + r) * 16 + c]);
            k[r] = f2bf(SC * Wk[(4 * g + r) * 16 + c]);
            v[r] = f2bf(sWvo[(4 * g + r) * 16 + c]);
        }
        #pragma unroll
        for (int r = 4; r < 8; ++r) { q[r] = 0; k[r] = 0; v[r] = 0; }
        ((bf16x8*)ws)[WS_WQ + tid] = q;
        ((bf16x8*)ws)[WS_WK + tid] = k;
        ((bf16x8*)ws)[WS_WV + tid] = v;
    }
    if (tid < 16) {
        ws[WS_BK + tid] = SC * bk[tid];
        float bb = bo[tid];
        #pragma unroll
        for (int c = 0; c < 16; ++c) bb += bv[c] * Wo[c * 16 + tid];
        ws[WS_BVO + tid] = bb;
    }
}

// grid: NB*4 blocks; block = (b, quarter q); wave w handles i = q*16 + w*4 + t
__global__ __launch_bounds__(256, 4) void attn_kernel(
    const float* __restrict__ inp,
    const float* __restrict__ bq,
    const float* __restrict__ ws,
    float* __restrict__ out)
{
    __shared__ float sRed[WPB * 64 * OUTC];   // 20 KiB

    const int tid  = threadIdx.x;
    const int lane = tid & 63;
    const int w    = tid >> 6;
    const int g    = lane >> 4;
    const int c    = lane & 15;
    const int b    = blockIdx.x >> 2;
    const int q    = blockIdx.x & 3;

    const bf16x8 wq = ((const bf16x8*)ws)[WS_WQ + lane];
    const bf16x8 wk = ((const bf16x8*)ws)[WS_WK + lane];
    const bf16x8 wv = ((const bf16x8*)ws)[WS_WV + lane];
    const float4 bq_r  = *(const float4*)(bq + 4 * g);
    const float4 bk_r  = *(const float4*)(ws + WS_BK + 4 * g);
    const float4 bvo_r = *(const float4*)(ws + WS_BVO + 4 * g);

    // base of this wave's first task
    const size_t idx0 = (size_t)b * NA + (size_t)(q * 16 + w * TPW);
    const float* dynp = inp + idx0 * OBS + MOVE + (size_t)c * ROWS + 4 * g;

    const f32x4 zc = {0.f, 0.f, 0.f, 0.f};
    f32x4 acc[4] = {zc, zc, zc, zc};

    // prefetch task 0's dyn rows (tile i: rows 16i+c, elems 4g..4g+3)
    float4 f0 = *(const float4*)(dynp + 0 * 16 * ROWS);
    float4 f1 = *(const float4*)(dynp + 1 * 16 * ROWS);
    float4 f2 = *(const float4*)(dynp + 2 * 16 * ROWS);
    float4 f3 = *(const float4*)(dynp + 3 * 16 * ROWS);

    #pragma unroll
    for (int t = 0; t < TPW; ++t) {
        bf16x8 dy[4];
        dy[0] = mkfrag4(f0.x, f0.y, f0.z, f0.w);
        dy[1] = mkfrag4(f1.x, f1.y, f1.z, f1.w);
        dy[2] = mkfrag4(f2.x, f2.y, f2.z, f2.w);
        dy[3] = mkfrag4(f3.x, f3.y, f3.z, f3.w);

        // issue next task's loads NOW; they fly under this task's compute
        if (t + 1 < TPW) {
            const float* np = dynp + (size_t)(t + 1) * OBS;
            f0 = *(const float4*)(np + 0 * 16 * ROWS);
            f1 = *(const float4*)(np + 1 * 16 * ROWS);
            f2 = *(const float4*)(np + 2 * 16 * ROWS);
            f3 = *(const float4*)(np + 3 * 16 * ROWS);
        }

        // projections: Q^T, K^T (scaled), V' = dyn @ (Wv@Wo)
        bf16x8 qb[4], kb[4];
        f32x4 vC[4];
        #pragma unroll
        for (int i = 0; i < 4; ++i) {
            f32x4 qT = __builtin_amdgcn_mfma_f32_16x16x32_bf16(wq, dy[i], zc, 0, 0, 0);
            f32x4 kT = __builtin_amdgcn_mfma_f32_16x16x32_bf16(wk, dy[i], zc, 0, 0, 0);
            vC[i]    = __builtin_amdgcn_mfma_f32_16x16x32_bf16(dy[i], wv, zc, 0, 0, 0);
            qb[i] = mkfrag4(qT[0] + bq_r.x, qT[1] + bq_r.y, qT[2] + bq_r.z, qT[3] + bq_r.w);
            kb[i] = mkfrag4(kT[0] + bk_r.x, kT[1] + bk_r.y, kT[2] + bk_r.z, kT[3] + bk_r.w);
        }
        const bf16x8 vb_lo = mkfrag8(vC[0], vC[1]);
        const bf16x8 vb_hi = mkfrag8(vC[2], vC[3]);

        #pragma unroll
        for (int j = 0; j < 4; ++j) {
            f32x4 s0 = __builtin_amdgcn_mfma_f32_16x16x32_bf16(kb[0], qb[j], zc, 0, 0, 0);
            f32x4 s1 = __builtin_amdgcn_mfma_f32_16x16x32_bf16(kb[1], qb[j], zc, 0, 0, 0);
            f32x4 s2 = __builtin_amdgcn_mfma_f32_16x16x32_bf16(kb[2], qb[j], zc, 0, 0, 0);
            f32x4 s3 = __builtin_amdgcn_mfma_f32_16x16x32_bf16(kb[3], qb[j], zc, 0, 0, 0);

            float part = 0.f;
            #pragma unroll
            for (int r = 0; r < 4; ++r) {
                s0[r] = __builtin_amdgcn_exp2f(s0[r]); part += s0[r];
                s1[r] = __builtin_amdgcn_exp2f(s1[r]); part += s1[r];
                s2[r] = __builtin_amdgcn_exp2f(s2[r]); part += s2[r];
                s3[r] = __builtin_amdgcn_exp2f(s3[r]); part += s3[r];
            }
            part += __shfl_xor(part, 16);
            part += __shfl_xor(part, 32);
            float inv = __builtin_amdgcn_rcpf(part);

            bf16x8 p_lo = mkfrag8(s0, s1);
            bf16x8 p_hi = mkfrag8(s2, s3);

            f32x4 ot;
            ot = __builtin_amdgcn_mfma_f32_16x16x32_bf16(vb_lo, p_lo, zc, 0, 0, 0);
            ot = __builtin_amdgcn_mfma_f32_16x16x32_bf16(vb_hi, p_hi, ot, 0, 0, 0);

            // normalize, +bvo, relu, accumulate over this wave's tasks
            acc[j][0] += fmaxf(fmaf(ot[0], inv, bvo_r.x), 0.f);
            acc[j][1] += fmaxf(fmaf(ot[1], inv, bvo_r.y), 0.f);
            acc[j][2] += fmaxf(fmaf(ot[2], inv, bvo_r.z), 0.f);
            acc[j][3] += fmaxf(fmaf(ot[3], inv, bvo_r.w), 0.f);
        }
    }

    // stage per-wave sums: sRed[w][t=16j+c][d=4g+r]
    #pragma unroll
    for (int j = 0; j < 4; ++j) {
        float4 st = make_float4(acc[j][0], acc[j][1], acc[j][2], acc[j][3]);
        *(float4*)(&sRed[(w * 64 + 16 * j + c) * OUTC + 4 * g]) = st;
    }
    __syncthreads();

    // block reduce over 4 waves, one atomic per element (4 contending blocks per b)
    {
        int t = tid >> 2, dq = tid & 3;
        const float4 a0 = *(const float4*)(&sRed[(0 * 64 + t) * OUTC + dq * 4]);
        const float4 a1 = *(const float4*)(&sRed[(1 * 64 + t) * OUTC + dq * 4]);
        const float4 a2 = *(const float4*)(&sRed[(2 * 64 + t) * OUTC + dq * 4]);
        const float4 a3 = *(const float4*)(&sRed[(3 * 64 + t) * OUTC + dq * 4]);
        float s0 = a0.x + a1.x + a2.x + a3.x;
        float s1 = a0.y + a1.y + a2.y + a3.y;
        float s2 = a0.z + a1.z + a2.z + a3.z;
        float s3 = a0.w + a1.w + a2.w + a3.w;
        float* op = out + ((size_t)b * NA + t) * OUTC + MOVE + dq * 4;
        atomicAdd(op + 0, s0);
        atomicAdd(op + 1, s1);
        atomicAdd(op + 2, s2);
        atomicAdd(op + 3, s3);
    }
}

extern "C" void kernel_launch(void* const* d_in, const int* in_sizes, int n_in,
                              void* d_out, int out_size, void* d_ws, size_t ws_size,
                              hipStream_t stream) {
    const float* inp = (const float*)d_in[0];
    const float* Wq  = (const float*)d_in[1];
    const float* bq  = (const float*)d_in[2];
    const float* Wk  = (const float*)d_in[3];
    const float* bk  = (const float*)d_in[4];
    const float* Wv  = (const float*)d_in[5];
    const float* bv  = (const float*)d_in[6];
    const float* Wo  = (const float*)d_in[7];
    const float* bo  = (const float*)d_in[8];
    float* out = (float*)d_out;
    float* ws  = (float*)d_ws;

    hipLaunchKernelGGL(prep_kernel, dim3(1), dim3(256), 0, stream, Wq, Wk, bk, Wv, bv, Wo, bo, ws);
    hipLaunchKernelGGL(init_out_kernel, dim3(NTASK / 256), dim3(256), 0, stream, inp, out);
    hipLaunchKernelGGL(attn_kernel, dim3(NB * 4), dim3(256), 0, stream,
                       inp, bq, ws, out);
}

// Round 7
// 45.502 us; speedup vs baseline: 2.2484x; 2.2484x over previous
//
#include <hip/hip_runtime.h>

#define NA 64
#define MOVE 4
#define OBS 5124
#define ROWS 80        // dyn inner row stride (elements)
#define NB 256
#define NTASK (NB * NA)   // 16384 (b,i) tasks
#define OUTC 20
#define WPB 4             // waves per block (1 task per wave)
#define NPART 16          // blocks per batch element

// ws layout: bf16x8 frag tables [0..191], floats [768..799] biases,
// partials at float offset WS_PART: [b][p][t*16+d] = 256*16*1024 floats (16.8 MB)
#define WS_WQ 0
#define WS_WK 64
#define WS_WV 128
#define WS_BK 768
#define WS_BVO 784
#define WS_PART 1024

typedef __attribute__((ext_vector_type(8))) short bf16x8;
typedef __attribute__((ext_vector_type(4))) float f32x4;

__device__ __forceinline__ short f2bf(float f) {
    __bf16 h = (__bf16)f;
    return __builtin_bit_cast(short, h);
}
__device__ __forceinline__ bf16x8 mkfrag4(float a, float b, float c, float d) {
    bf16x8 t;
    t[0] = f2bf(a); t[1] = f2bf(b); t[2] = f2bf(c); t[3] = f2bf(d);
    t[4] = 0; t[5] = 0; t[6] = 0; t[7] = 0;
    return t;
}
__device__ __forceinline__ bf16x8 mkfrag8(f32x4 lo, f32x4 hi) {
    bf16x8 t;
    t[0] = f2bf(lo[0]); t[1] = f2bf(lo[1]); t[2] = f2bf(lo[2]); t[3] = f2bf(lo[3]);
    t[4] = f2bf(hi[0]); t[5] = f2bf(hi[1]); t[6] = f2bf(hi[2]); t[7] = f2bf(hi[3]);
    return t;
}

__global__ __launch_bounds__(256) void prep_kernel(
    const float* __restrict__ Wq,
    const float* __restrict__ Wk, const float* __restrict__ bk,
    const float* __restrict__ Wv, const float* __restrict__ bv,
    const float* __restrict__ Wo, const float* __restrict__ bo,
    float* __restrict__ ws)
{
    __shared__ float sWvo[256];
    const float SC = 0.36067376022224085f;   // 0.25 * log2(e)
    int tid = threadIdx.x;
    {
        int e = tid >> 4, d = tid & 15;
        float acc = 0.f;
        #pragma unroll
        for (int c = 0; c < 16; ++c) acc += Wv[e * 16 + c] * Wo[c * 16 + d];
        sWvo[e * 16 + d] = acc;
    }
    __syncthreads();
    if (tid < 64) {
        int g = tid >> 4, c = tid & 15;
        bf16x8 q, k, v;
        #pragma unroll
        for (int r = 0; r < 4; ++r) {
            q[r] = f2bf(Wq[(4 * g + r) * 16 + c]);
            k[r] = f2bf(SC * Wk[(4 * g + r) * 16 + c]);
            v[r] = f2bf(sWvo[(4 * g + r) * 16 + c]);
        }
        #pragma unroll
        for (int r = 4; r < 8; ++r) { q[r] = 0; k[r] = 0; v[r] = 0; }
        ((bf16x8*)ws)[WS_WQ + tid] = q;
        ((bf16x8*)ws)[WS_WK + tid] = k;
        ((bf16x8*)ws)[WS_WV + tid] = v;
    }
    if (tid < 16) {
        ws[WS_BK + tid] = SC * bk[tid];
        float bb = bo[tid];
        #pragma unroll
        for (int c = 0; c < 16; ++c) bb += bv[c] * Wo[c * 16 + tid];
        ws[WS_BVO + tid] = bb;
    }
}

// grid: NTASK/WPB = 4096 blocks; block = (b, p): tasks idx = blockIdx*4 + w
__global__ __launch_bounds__(256, 4) void attn_kernel(
    const float* __restrict__ inp,
    const float* __restrict__ bq,
    float* __restrict__ ws)
{
    __shared__ float sRed[WPB * 64 * OUTC];   // 20 KiB

    const int tid  = threadIdx.x;
    const int lane = tid & 63;
    const int w    = tid >> 6;
    const int idx  = blockIdx.x * WPB + w;    // b*NA + i
    const int g    = lane >> 4;
    const int c    = lane & 15;

    const bf16x8 wq = ((const bf16x8*)ws)[WS_WQ + lane];
    const bf16x8 wk = ((const bf16x8*)ws)[WS_WK + lane];
    const bf16x8 wv = ((const bf16x8*)ws)[WS_WV + lane];
    const float4 bq_r  = *(const float4*)(bq + 4 * g);
    const float4 bk_r  = *(const float4*)(ws + WS_BK + 4 * g);
    const float4 bvo_r = *(const float4*)(ws + WS_BVO + 4 * g);

    // dyn fragments: tile i holds rows a = 16i+c, elems e = 4g..4g+3
    const float* dynp = inp + (size_t)idx * OBS + MOVE;
    bf16x8 dy[4];
    #pragma unroll
    for (int i = 0; i < 4; ++i) {
        float4 f = *(const float4*)(dynp + (16 * i + c) * ROWS + 4 * g);
        dy[i] = mkfrag4(f.x, f.y, f.z, f.w);
    }

    const f32x4 zc = {0.f, 0.f, 0.f, 0.f};

    // projections: Q^T, K^T (scaled), V' = dyn @ (Wv@Wo)
    bf16x8 qb[4], kb[4];
    f32x4 vC[4];
    #pragma unroll
    for (int i = 0; i < 4; ++i) {
        f32x4 qT = __builtin_amdgcn_mfma_f32_16x16x32_bf16(wq, dy[i], zc, 0, 0, 0);
        f32x4 kT = __builtin_amdgcn_mfma_f32_16x16x32_bf16(wk, dy[i], zc, 0, 0, 0);
        vC[i]    = __builtin_amdgcn_mfma_f32_16x16x32_bf16(dy[i], wv, zc, 0, 0, 0);
        qb[i] = mkfrag4(qT[0] + bq_r.x, qT[1] + bq_r.y, qT[2] + bq_r.z, qT[3] + bq_r.w);
        kb[i] = mkfrag4(kT[0] + bk_r.x, kT[1] + bk_r.y, kT[2] + bk_r.z, kT[3] + bk_r.w);
    }
    const bf16x8 vb_lo = mkfrag8(vC[0], vC[1]);
    const bf16x8 vb_hi = mkfrag8(vC[2], vC[3]);

    // per t-tile j: S^T, streaming no-max softmax (exp2, scale folded), packed PV
    #pragma unroll
    for (int j = 0; j < 4; ++j) {
        f32x4 s0 = __builtin_amdgcn_mfma_f32_16x16x32_bf16(kb[0], qb[j], zc, 0, 0, 0);
        f32x4 s1 = __builtin_amdgcn_mfma_f32_16x16x32_bf16(kb[1], qb[j], zc, 0, 0, 0);
        f32x4 s2 = __builtin_amdgcn_mfma_f32_16x16x32_bf16(kb[2], qb[j], zc, 0, 0, 0);
        f32x4 s3 = __builtin_amdgcn_mfma_f32_16x16x32_bf16(kb[3], qb[j], zc, 0, 0, 0);

        float part = 0.f;
        #pragma unroll
        for (int r = 0; r < 4; ++r) {
            s0[r] = __builtin_amdgcn_exp2f(s0[r]); part += s0[r];
            s1[r] = __builtin_amdgcn_exp2f(s1[r]); part += s1[r];
            s2[r] = __builtin_amdgcn_exp2f(s2[r]); part += s2[r];
            s3[r] = __builtin_amdgcn_exp2f(s3[r]); part += s3[r];
        }
        part += __shfl_xor(part, 16);
        part += __shfl_xor(part, 32);
        float inv = __builtin_amdgcn_rcpf(part);

        bf16x8 p_lo = mkfrag8(s0, s1);
        bf16x8 p_hi = mkfrag8(s2, s3);

        f32x4 ot;
        ot = __builtin_amdgcn_mfma_f32_16x16x32_bf16(vb_lo, p_lo, zc, 0, 0, 0);
        ot = __builtin_amdgcn_mfma_f32_16x16x32_bf16(vb_hi, p_hi, ot, 0, 0, 0);

        float4 st;
        st.x = fmaxf(fmaf(ot[0], inv, bvo_r.x), 0.f);
        st.y = fmaxf(fmaf(ot[1], inv, bvo_r.y), 0.f);
        st.z = fmaxf(fmaf(ot[2], inv, bvo_r.z), 0.f);
        st.w = fmaxf(fmaf(ot[3], inv, bvo_r.w), 0.f);
        *(float4*)(&sRed[(w * 64 + 16 * j + c) * OUTC + 4 * g]) = st;
    }

    __syncthreads();

    // block reduce over 4 waves -> plain coalesced partial store (NO atomics)
    {
        int t = tid >> 2, dq = tid & 3;
        const float4 a0 = *(const float4*)(&sRed[(0 * 64 + t) * OUTC + dq * 4]);
        const float4 a1 = *(const float4*)(&sRed[(1 * 64 + t) * OUTC + dq * 4]);
        const float4 a2 = *(const float4*)(&sRed[(2 * 64 + t) * OUTC + dq * 4]);
        const float4 a3 = *(const float4*)(&sRed[(3 * 64 + t) * OUTC + dq * 4]);
        float4 st;
        st.x = a0.x + a1.x + a2.x + a3.x;
        st.y = a0.y + a1.y + a2.y + a3.y;
        st.z = a0.z + a1.z + a2.z + a3.z;
        st.w = a0.w + a1.w + a2.w + a3.w;
        // partial slot: ws[WS_PART + blockIdx*1024 + t*16 + dq*4]
        *(float4*)(ws + WS_PART + (size_t)blockIdx.x * 1024 + t * 16 + dq * 4) = st;
    }
}

// grid: NB blocks; sums NPART partials per output element + MOVE passthrough
__global__ __launch_bounds__(256) void reduce_kernel(
    const float* __restrict__ inp, const float* __restrict__ ws,
    float* __restrict__ out)
{
    const int b   = blockIdx.x;
    const int tid = threadIdx.x;
    const float* pb = ws + WS_PART + (size_t)b * (NPART * 1024);

    if (tid < 64) {
        float4 mv = *(const float4*)(inp + ((size_t)b * NA + tid) * OBS);
        *(float4*)(out + ((size_t)b * NA + tid) * OUTC) = mv;
    }
    #pragma unroll
    for (int r = 0; r < 4; ++r) {
        int e = tid + r * 256;           // e = t*16 + d, 0..1023
        float s = 0.f;
        #pragma unroll
        for (int p = 0; p < NPART; ++p) s += pb[p * 1024 + e];
        int t = e >> 4, d = e & 15;
        out[((size_t)b * NA + t) * OUTC + MOVE + d] = s;
    }
}

extern "C" void kernel_launch(void* const* d_in, const int* in_sizes, int n_in,
                              void* d_out, int out_size, void* d_ws, size_t ws_size,
                              hipStream_t stream) {
    const float* inp = (const float*)d_in[0];
    const float* Wq  = (const float*)d_in[1];
    const float* bq  = (const float*)d_in[2];
    const float* Wk  = (const float*)d_in[3];
    const float* bk  = (const float*)d_in[4];
    const float* Wv  = (const float*)d_in[5];
    const float* bv  = (const float*)d_in[6];
    const float* Wo  = (const float*)d_in[7];
    const float* bo  = (const float*)d_in[8];
    float* out = (float*)d_out;
    float* ws  = (float*)d_ws;

    hipLaunchKernelGGL(prep_kernel, dim3(1), dim3(256), 0, stream, Wq, Wk, bk, Wv, bv, Wo, bo, ws);
    hipLaunchKernelGGL(attn_kernel, dim3(NTASK / WPB), dim3(256), 0, stream, inp, bq, ws);
    hipLaunchKernelGGL(reduce_kernel, dim3(NB), dim3(256), 0, stream, inp, ws, out);
}